// Round 5
// baseline (289.750 us; speedup 1.0000x reference)
//
#include <hip/hip_runtime.h>
#include <cstdint>
#include <cmath>

#define RLN2 1.44269504088896340736f

typedef __attribute__((ext_vector_type(8))) short short8;
typedef __attribute__((ext_vector_type(4))) short short4v;
typedef __attribute__((ext_vector_type(4))) float f32x4;
typedef __attribute__((ext_vector_type(16))) float f32x16;
typedef __attribute__((ext_vector_type(4))) unsigned int uint4v;

__device__ __forceinline__ unsigned short f2bf(float f) {
  unsigned int u = __float_as_uint(f);
  u += 0x7fffu + ((u >> 16) & 1u);
  return (unsigned short)(u >> 16);
}

__device__ __forceinline__ unsigned int cvt_pk_bf16(float lo, float hi) {
  unsigned int r;
  asm("v_cvt_pk_bf16_f32 %0, %1, %2" : "=v"(r) : "v"(lo), "v"(hi));
  return r;
}

__device__ __forceinline__ float fast_exp2(float x) {
#if __has_builtin(__builtin_amdgcn_exp2f)
  return __builtin_amdgcn_exp2f(x);
#else
  return exp2f(x);
#endif
}

__device__ __forceinline__ void gload16(const void* g, void* l) {
  __builtin_amdgcn_global_load_lds(
      (const __attribute__((address_space(1))) unsigned int*)g,
      (__attribute__((address_space(3))) unsigned int*)l,
      16, 0, 0);
}

// ---------------- fp32 -> bf16 conversions ----------------

__global__ void __launch_bounds__(256) k_cvt_hs(const float* __restrict__ src,
                                                unsigned short* __restrict__ dst) {
  size_t i = (size_t)blockIdx.x * 256 + threadIdx.x;
  const float4* s = (const float4*)src + i * 2;
  float4 a = s[0], b = s[1];
  short8 o;
  o[0] = (short)f2bf(a.x); o[1] = (short)f2bf(a.y); o[2] = (short)f2bf(a.z); o[3] = (short)f2bf(a.w);
  o[4] = (short)f2bf(b.x); o[5] = (short)f2bf(b.y); o[6] = (short)f2bf(b.z); o[7] = (short)f2bf(b.w);
  ((short8*)dst)[i] = o;
}

__global__ void __launch_bounds__(256) k_cvt_w(const float* __restrict__ Wq,
                                               const float* __restrict__ Wk,
                                               const float* __restrict__ Wv,
                                               unsigned short* __restrict__ dst) {
  size_t i = (size_t)blockIdx.x * 256 + threadIdx.x;
  int e = (int)(i * 8);
  int n = e >> 10, c = e & 1023;
  const float* row = (n < 1024) ? (Wq + (size_t)n * 1024)
                   : (n < 2048) ? (Wk + (size_t)(n - 1024) * 1024)
                                : (Wv + (size_t)(n - 2048) * 1024);
  const float4* s = (const float4*)(row + c);
  float4 a = s[0], b = s[1];
  short8 o;
  o[0] = (short)f2bf(a.x); o[1] = (short)f2bf(a.y); o[2] = (short)f2bf(a.z); o[3] = (short)f2bf(a.w);
  o[4] = (short)f2bf(b.x); o[5] = (short)f2bf(b.y); o[6] = (short)f2bf(b.z); o[7] = (short)f2bf(b.w);
  ((short8*)dst)[i] = o;
}

__global__ void __launch_bounds__(256) k_seg(const int* __restrict__ seg_ids,
                                             const float* __restrict__ seg_table,
                                             unsigned short* __restrict__ Kaug) {
  size_t i = (size_t)blockIdx.x * 256 + threadIdx.x;
  int e = (int)(i * 8);
  int jl = e >> 10;
  int r  = e & 1023;
  int sid = seg_ids[jl];
  const float4* s = (const float4*)(seg_table + (size_t)sid * 1024 + r);
  float4 a = s[0], b = s[1];
  short8 o;
  o[0] = (short)f2bf(a.x); o[1] = (short)f2bf(a.y); o[2] = (short)f2bf(a.z); o[3] = (short)f2bf(a.w);
  o[4] = (short)f2bf(b.x); o[5] = (short)f2bf(b.y); o[6] = (short)f2bf(b.z); o[7] = (short)f2bf(b.w);
  int b_ = jl >> 11, j = jl & 2047;
  int h = r >> 6, d = r & 63;
  size_t off = ((size_t)(b_ * 16 + h) * 2048 + j) * 128 + 64 + d;
  *(short8*)(Kaug + off) = o;
}

// ---------------- fused QKV GEMM (NT) ----------------
// epilogue: Q -> Qaug (scaled halves), K -> Kaug first half,
// V -> Vt DIRECTLY: [bh][64 dv][2048 pos] with the PV k-permutation folded in:
//   k = i&63 = m*16 + g*4 + r  ->  pos = 32*((m>>1)&1) + 16*(m&1) + 8*(g&1) + 4*((g>>1)&1) + r
// (r=0..3 consecutive -> one 8B packed store)
__global__ void __launch_bounds__(256) k_gemm(const unsigned short* __restrict__ A,
                                              const unsigned short* __restrict__ Bw,
                                              const float* __restrict__ bq,
                                              const float* __restrict__ bv,
                                              const float* __restrict__ bqs,
                                              unsigned short* __restrict__ Qaug,
                                              unsigned short* __restrict__ Kaug,
                                              unsigned short* __restrict__ Vt) {
  __shared__ unsigned short As[128 * 32];
  __shared__ unsigned short Bs[128 * 32];
  int n0 = blockIdx.x * 128;
  int m0 = blockIdx.y * 128;
  int tid = threadIdx.x;
  int w = tid >> 6, lane = tid & 63;
  int wr = (w >> 1) * 64, wc = (w & 1) * 64;
  int rA = lane & 15;
  int kg = (lane >> 4) * 16;
  f32x4 acc[4][4] = {};
  const char* Ab = (const char*)A;
  const char* Bb = (const char*)Bw;

  for (int kt = 0; kt < 32; ++kt) {
    int kb0 = kt * 64;
#pragma unroll
    for (int c = 0; c < 2; ++c) {
      int chunk = w * 2 + c;
      int y = chunk * 1024 + lane * 16;
      int row = y >> 6, colb = y & 63;
      gload16(Ab + (size_t)(m0 + row) * 2048 + kb0 + colb, (char*)As + chunk * 1024);
      gload16(Bb + (size_t)(n0 + row) * 2048 + kb0 + colb, (char*)Bs + chunk * 1024);
    }
    __syncthreads();
    short8 af[4], bfr[4];
#pragma unroll
    for (int m = 0; m < 4; ++m)
      af[m] = *(const short8*)((const char*)As + (wr + m * 16 + rA) * 64 + kg);
#pragma unroll
    for (int n = 0; n < 4; ++n)
      bfr[n] = *(const short8*)((const char*)Bs + (wc + n * 16 + rA) * 64 + kg);
#pragma unroll
    for (int m = 0; m < 4; ++m)
#pragma unroll
      for (int n = 0; n < 4; ++n)
        acc[m][n] = __builtin_amdgcn_mfma_f32_16x16x32_bf16(af[m], bfr[n], acc[m][n], 0, 0, 0);
    __syncthreads();
  }

  int seg = n0 >> 10;
  int colbase = n0 & 1023;
  int g = lane >> 4;
#pragma unroll
  for (int n = 0; n < 4; ++n) {
    int o = colbase + wc + n * 16 + (lane & 15);
    int h = o >> 6, d = o & 63;
    float bias = 0.f, bqsv = 0.f;
    if (seg == 0) { bias = bq[o]; bqsv = bqs[o]; }
    else if (seg == 2) { bias = bv[o]; }
#pragma unroll
    for (int m = 0; m < 4; ++m) {
      if (seg == 2) {
        int i = m0 + wr + m * 16 + g * 4;  // r=0 token
        int b_ = i >> 11, sdx = i & 2047;
        int bh = b_ * 16 + h;
        int pos = (sdx & ~63) + 32 * ((m >> 1) & 1) + 16 * (m & 1) + 8 * (g & 1) + 4 * ((g >> 1) & 1);
        short4v pv;
#pragma unroll
        for (int r = 0; r < 4; ++r)
          pv[r] = (short)f2bf(acc[m][n][r] + bias);
        *(short4v*)(Vt + (size_t)bh * 131072 + (size_t)d * 2048 + pos) = pv;
      } else {
#pragma unroll
        for (int r = 0; r < 4; ++r) {
          int i = m0 + wr + m * 16 + g * 4 + r;
          int b_ = i >> 11, sdx = i & 2047;
          float val = acc[m][n][r];
          size_t tok = (size_t)(b_ * 16 + h) * 2048 + sdx;
          if (seg == 0) {
            float qv = val + bias;
            Qaug[tok * 128 + d]      = f2bf(qv * (0.125f * RLN2));
            Qaug[tok * 128 + 64 + d] = f2bf((qv + bqsv) * RLN2);
          } else {
            Kaug[tok * 128 + d] = f2bf(val);
          }
        }
      }
    }
  }
}

// ---------------- flash attention, 32x32x16 MFMA, 64 q-rows/wave ----------------
// Two q-halves (q, q+32) share every K/V LDS fragment read (A-fragments are
// lane-only-dependent) -> LDS traffic per unit work halves vs 32q/wave.
// S^T = mfma(A=K, B=Q): lane owns q=lane&31; s[reg] holds k = 4*hi+(reg&3)+8*(reg>>2).
// PV: O = mfma(A=Vt-frag, B=P) with k-permuted Vt (see k_gemm) so P B-frags are
// consecutive S regs. LDS: K rows 256B, V rows 128B, XOR swizzle ^((row&7)<<4).
__global__ void __launch_bounds__(256, 2) k_attn(const unsigned short* __restrict__ Qaug,
                                                 const unsigned short* __restrict__ Kaug,
                                                 const unsigned short* __restrict__ Vt,
                                                 const float* __restrict__ mask,
                                                 float* __restrict__ out) {
  __shared__ char smem[49152];
  char* Ksb = smem;          // 2 x 16K
  char* Vsb = smem + 32768;  // 2 x 8K

  int qt = blockIdx.x, h = blockIdx.y, b_ = blockIdx.z;
  int bh = b_ * 16 + h;
  int i0 = qt * 256;
  int tid = threadIdx.x, w = tid >> 6, lane = tid & 63;
  int q = lane & 31, hi = lane >> 5;
  int swzq = (q & 7) << 4;
  const char* Qg = (const char*)Qaug + (size_t)bh * 2048 * 256;
  const char* Kg = (const char*)Kaug + (size_t)bh * 2048 * 256;
  const char* Vg = (const char*)Vt + (size_t)bh * 64 * 4096;
  const float* maskb = mask + (size_t)b_ * 2048;

  int foff[8];
#pragma unroll
  for (int ds = 0; ds < 8; ++ds)
    foff[ds] = (ds * 32 + hi * 16) ^ swzq;

  int kst_row = lane >> 4, kst_x = (lane & 15) * 16;
  int vst_dv = lane >> 3;
  int vst_x = ((lane & 7) * 16) ^ ((vst_dv & 7) << 4);

  // ---- stage tile 0 ----
#pragma unroll
  for (int c = 0; c < 4; ++c) {
    int ck = w * 4 + c;
    int krow = ck * 4 + kst_row;
    gload16(Kg + (size_t)krow * 256 + (kst_x ^ ((krow & 7) << 4)), Ksb + ck * 1024);
  }
#pragma unroll
  for (int c = 0; c < 2; ++c) {
    int ck = w * 2 + c;
    int dv = ck * 8 + vst_dv;
    gload16(Vg + (size_t)dv * 4096 + vst_x, Vsb + ck * 1024);
  }

  // Q fragments for both q-halves: rows i0 + w*64 + q and +32
  short8 qfA[8], qfB[8];
  {
    const char* qrowA = Qg + (size_t)(i0 + w * 64 + q) * 256 + hi * 16;
    const char* qrowB = qrowA + 32 * 256;
#pragma unroll
    for (int ds = 0; ds < 8; ++ds) {
      qfA[ds] = *(const short8*)(qrowA + ds * 32);
      qfB[ds] = *(const short8*)(qrowB + ds * 32);
    }
  }
  __syncthreads();  // K0/V0 resident

  float mA = -1e30f, lA = 0.f, mB = -1e30f, lB = 0.f;
  f32x16 accA0 = {}, accA1 = {}, accB0 = {}, accB1 = {};

  for (int t = 0; t < 32; ++t) {
    int cur = t & 1, nxt = cur ^ 1;
    int j0 = t * 64;
    if (t < 31) {
      int jn = j0 + 64;
      char* kd = Ksb + nxt * 16384;
      char* vd = Vsb + nxt * 8192;
#pragma unroll
      for (int c = 0; c < 4; ++c) {
        int ck = w * 4 + c;
        int krow = ck * 4 + kst_row;
        gload16(Kg + (size_t)(jn + krow) * 256 + (kst_x ^ ((krow & 7) << 4)), kd + ck * 1024);
      }
#pragma unroll
      for (int c = 0; c < 2; ++c) {
        int ck = w * 2 + c;
        int dv = ck * 8 + vst_dv;
        gload16(Vg + (size_t)dv * 4096 + jn * 2 + vst_x, vd + ck * 1024);
      }
    }
    const char* kq = Ksb + cur * 16384 + q * 256;
    const char* vq = Vsb + cur * 8192 + q * 128;

    // ---- S^T for both q-halves, sharing K fragment reads ----
    f32x16 sA0 = {}, sA1 = {}, sB0 = {}, sB1 = {};
    __builtin_amdgcn_s_setprio(1);
#pragma unroll
    for (int ds = 0; ds < 8; ++ds) {
      short8 kf0 = *(const short8*)(kq + foff[ds]);
      short8 kf1 = *(const short8*)(kq + foff[ds] + 8192);
      sA0 = __builtin_amdgcn_mfma_f32_32x32x16_bf16(kf0, qfA[ds], sA0, 0, 0, 0);
      sB0 = __builtin_amdgcn_mfma_f32_32x32x16_bf16(kf0, qfB[ds], sB0, 0, 0, 0);
      sA1 = __builtin_amdgcn_mfma_f32_32x32x16_bf16(kf1, qfA[ds], sA1, 0, 0, 0);
      sB1 = __builtin_amdgcn_mfma_f32_32x32x16_bf16(kf1, qfB[ds], sB1, 0, 0, 0);
    }
    __builtin_amdgcn_s_setprio(0);

    // ---- mask add (k-dependent only: shared by both halves) ----
#pragma unroll
    for (int c = 0; c < 4; ++c) {
      f32x4 mv0 = *(const f32x4*)(maskb + j0 + 8 * c + 4 * hi);
      f32x4 mv1 = *(const f32x4*)(maskb + j0 + 32 + 8 * c + 4 * hi);
#pragma unroll
      for (int r = 0; r < 4; ++r) {
        float a0 = mv0[r] * RLN2, a1 = mv1[r] * RLN2;
        sA0[4 * c + r] += a0; sB0[4 * c + r] += a0;
        sA1[4 * c + r] += a1; sB1[4 * c + r] += a1;
      }
    }

    // ---- online softmax per half (lane owns q; reduce across hi via xor 32) ----
    {
      float tm = -1e30f;
#pragma unroll
      for (int i = 0; i < 16; ++i) tm = fmaxf(tm, fmaxf(sA0[i], sA1[i]));
      tm = fmaxf(tm, __shfl_xor(tm, 32));
      if (__any(tm > mA + 8.0f)) {
        float mn = fmaxf(mA, tm);
        float alpha = fast_exp2(mA - mn);
        mA = mn; lA *= alpha;
#pragma unroll
        for (int i = 0; i < 16; ++i) { accA0[i] *= alpha; accA1[i] *= alpha; }
      }
      float ps = 0.f;
#pragma unroll
      for (int i = 0; i < 16; ++i) {
        float e0 = fast_exp2(sA0[i] - mA);
        float e1 = fast_exp2(sA1[i] - mA);
        sA0[i] = e0; sA1[i] = e1;
        ps += e0 + e1;
      }
      ps += __shfl_xor(ps, 32);
      lA += ps;
    }
    {
      float tm = -1e30f;
#pragma unroll
      for (int i = 0; i < 16; ++i) tm = fmaxf(tm, fmaxf(sB0[i], sB1[i]));
      tm = fmaxf(tm, __shfl_xor(tm, 32));
      if (__any(tm > mB + 8.0f)) {
        float mn = fmaxf(mB, tm);
        float alpha = fast_exp2(mB - mn);
        mB = mn; lB *= alpha;
#pragma unroll
        for (int i = 0; i < 16; ++i) { accB0[i] *= alpha; accB1[i] *= alpha; }
      }
      float ps = 0.f;
#pragma unroll
      for (int i = 0; i < 16; ++i) {
        float e0 = fast_exp2(sB0[i] - mB);
        float e1 = fast_exp2(sB1[i] - mB);
        sB0[i] = e0; sB1[i] = e1;
        ps += e0 + e1;
      }
      ps += __shfl_xor(ps, 32);
      lB += ps;
    }

    // ---- PV: both halves share V fragment reads; pk built just-in-time ----
    __builtin_amdgcn_s_setprio(1);
#pragma unroll
    for (int ks = 0; ks < 4; ++ks) {
      int o = 8 * (ks & 1);
      const f32x16& svA = (ks < 2) ? sA0 : sA1;
      const f32x16& svB = (ks < 2) ? sB0 : sB1;
      uint4v pa, pb;
      pa[0] = cvt_pk_bf16(svA[o + 0], svA[o + 1]);
      pa[1] = cvt_pk_bf16(svA[o + 2], svA[o + 3]);
      pa[2] = cvt_pk_bf16(svA[o + 4], svA[o + 5]);
      pa[3] = cvt_pk_bf16(svA[o + 6], svA[o + 7]);
      pb[0] = cvt_pk_bf16(svB[o + 0], svB[o + 1]);
      pb[1] = cvt_pk_bf16(svB[o + 2], svB[o + 3]);
      pb[2] = cvt_pk_bf16(svB[o + 4], svB[o + 5]);
      pb[3] = cvt_pk_bf16(svB[o + 6], svB[o + 7]);
      short8 pfA = __builtin_bit_cast(short8, pa);
      short8 pfB = __builtin_bit_cast(short8, pb);
      short8 vf0 = *(const short8*)(vq + foff[ks]);
      short8 vf1 = *(const short8*)(vq + foff[ks] + 4096);
      accA0 = __builtin_amdgcn_mfma_f32_32x32x16_bf16(vf0, pfA, accA0, 0, 0, 0);
      accB0 = __builtin_amdgcn_mfma_f32_32x32x16_bf16(vf0, pfB, accB0, 0, 0, 0);
      accA1 = __builtin_amdgcn_mfma_f32_32x32x16_bf16(vf1, pfA, accA1, 0, 0, 0);
      accB1 = __builtin_amdgcn_mfma_f32_32x32x16_bf16(vf1, pfB, accB1, 0, 0, 0);
    }
    __builtin_amdgcn_s_setprio(0);
    __syncthreads();  // prefetch drained; buffers swap
  }

  float invA = 1.0f / lA, invB = 1.0f / lB;
  float* orowA = out + ((size_t)b_ * 2048 + i0 + w * 64 + q) * 1024 + h * 64;
  float* orowB = orowA + 32 * 1024;
#pragma unroll
  for (int c = 0; c < 4; ++c) {
    f32x4 oa0, oa1, ob0, ob1;
#pragma unroll
    for (int r = 0; r < 4; ++r) {
      oa0[r] = accA0[4 * c + r] * invA;
      oa1[r] = accA1[4 * c + r] * invA;
      ob0[r] = accB0[4 * c + r] * invB;
      ob1[r] = accB1[4 * c + r] * invB;
    }
    *(f32x4*)(orowA + 8 * c + 4 * hi)      = oa0;
    *(f32x4*)(orowA + 32 + 8 * c + 4 * hi) = oa1;
    *(f32x4*)(orowB + 8 * c + 4 * hi)      = ob0;
    *(f32x4*)(orowB + 32 + 8 * c + 4 * hi) = ob1;
  }
}

extern "C" void kernel_launch(void* const* d_in, const int* in_sizes, int n_in,
                              void* d_out, int out_size, void* d_ws, size_t ws_size,
                              hipStream_t stream) {
  (void)in_sizes; (void)n_in; (void)out_size; (void)ws_size;
  const float* hs        = (const float*)d_in[0];
  const float* mask      = (const float*)d_in[1];
  const int*   seg_ids   = (const int*)d_in[2];
  const float* Wq        = (const float*)d_in[3];
  const float* bq        = (const float*)d_in[4];
  const float* Wk        = (const float*)d_in[5];
  const float* Wv        = (const float*)d_in[6];
  const float* bv        = (const float*)d_in[7];
  const float* seg_table = (const float*)d_in[8];
  const float* bqs       = (const float*)d_in[9];
  float* out = (float*)d_out;
  char* ws = (char*)d_ws;

  unsigned short* hsb  = (unsigned short*)(ws + 0);         // 16 MiB
  unsigned short* Wcat = (unsigned short*)(ws + 16777216);  // 6 MiB
  unsigned short* Qaug = (unsigned short*)(ws + 23068672);  // 32 MiB
  unsigned short* Kaug = (unsigned short*)(ws + 56623104);  // 32 MiB
  unsigned short* Vt   = (unsigned short*)(ws + 90177536);  // 16 MiB (written by gemm, permuted-transposed)

  k_cvt_hs<<<dim3(4096), dim3(256), 0, stream>>>(hs, hsb);
  k_cvt_w<<<dim3(1536), dim3(256), 0, stream>>>(Wq, Wk, Wv, Wcat);
  k_gemm<<<dim3(24, 64), dim3(256), 0, stream>>>(hsb, Wcat, bq, bv, bqs, Qaug, Kaug, Vt);
  k_seg<<<dim3(4096), dim3(256), 0, stream>>>(seg_ids, seg_table, Kaug);
  k_attn<<<dim3(8, 16, 4), dim3(256), 0, stream>>>(Qaug, Kaug, Vt, mask, out);
}